// Round 18
// baseline (105.446 us; speedup 1.0000x reference)
//
#include <hip/hip_runtime.h>

#define EMBED 1024
#define SEQL  2048
#define NHEAD 16
#define HDIM  64
#define NBATCH 2
#define MROWS 4096   // NBATCH*SEQL

typedef __attribute__((ext_vector_type(4))) float  f32x4;
typedef __attribute__((ext_vector_type(8))) __bf16 bf16x8;

// native HW bf16 convert (compiler fuses pairs into v_cvt_pk_bf16_f32)
__device__ __forceinline__ short f2bf(float f){
  __bf16 h = (__bf16)f;
  union { __bf16 h; short s; } u; u.h = h;
  return u.s;
}

#define GLDS(gp, lp) __builtin_amdgcn_global_load_lds( \
    (const __attribute__((address_space(1))) void*)(gp), \
    (__attribute__((address_space(3))) void*)(lp), 16, 0, 0)

#define WAITV(N) do { asm volatile("s_waitcnt vmcnt(" #N ")" ::: "memory"); \
                      __builtin_amdgcn_sched_barrier(0); } while(0)
#define BARRIER() do { __builtin_amdgcn_s_barrier(); \
                       __builtin_amdgcn_sched_barrier(0); } while(0)

// ------- prep: z=0..3 transpose W[z] fp32->bf16^T (64x64 float4 tiles);
//               z=4..7 convert x fp32->bf16 ------------------------------
__global__ __launch_bounds__(256) void prep_kernel(const float* __restrict__ x,
    const float* __restrict__ W0, const float* __restrict__ W1,
    const float* __restrict__ W2, const float* __restrict__ W3,
    short* __restrict__ Xb, short* __restrict__ WtAll){
  const int z = blockIdx.z;
  if (z < 4){
    __shared__ float T[64][65];          // 16.6 KB, +1 pad
    const int idx = blockIdx.y*32 + blockIdx.x;
    if (idx >= 256) return;              // 16x16 tiles of 64x64
    const float* W = (z==0)?W0:(z==1)?W1:(z==2)?W2:W3;
    short* Wt = WtAll + z*(EMBED*EMBED);
    const int bx = (idx & 15)*64;        // n-base
    const int by = (idx >> 4)*64;        // k-base
    const int c4 = (threadIdx.x & 15)*4;
    const int tr = threadIdx.x >> 4;     // 0..15
    #pragma unroll
    for (int i=0;i<4;++i){
      int r = 16*i + tr;
      float4 v = *(const float4*)(W + (by + r)*EMBED + bx + c4);
      T[c4+0][r] = v.x; T[c4+1][r] = v.y; T[c4+2][r] = v.z; T[c4+3][r] = v.w;
    }
    __syncthreads();
    #pragma unroll
    for (int i=0;i<4;++i){
      int n = 16*i + tr;
      short4 o;
      o.x = f2bf(T[n][c4+0]); o.y = f2bf(T[n][c4+1]);
      o.z = f2bf(T[n][c4+2]); o.w = f2bf(T[n][c4+3]);
      *(short4*)(Wt + (bx + n)*EMBED + by + c4) = o;
    }
  } else {
    const int blk = (z-4)*1024 + blockIdx.y*32 + blockIdx.x;
    const int i = (blk*256 + threadIdx.x)*4;
    float4 v = *(const float4*)(x + i);
    short4 o; o.x=f2bf(v.x); o.y=f2bf(v.y); o.z=f2bf(v.z); o.w=f2bf(v.w);
    *(short4*)(Xb + i) = o;
  }
}

// ======== QKV v3: 256x256 tile, BK=32, 3 rotating slots, 512 thr ===========
// 8 waves (2m x 4n); wave output 128x64: a[8] + b[4] = 12 ds_read_b128 per
// 32 MFMA (0.375 reads/MFMA vs 0.5/0.75 in prior rounds). One phase per
// K-tile: {stage(t+2): 4 GLDS -> 12 reads(t) -> barrier -> 32 MFMA(setprio)
// -> vmcnt(4) -> barrier}. Counted vmcnt keeps t+2 stages in flight; WAR:
// stage(t+2) targets slot of t-1 (its reads were consumed before the t-1
// end barrier, forced by the MFMA lgkmcnt). Swizzle: stage chunk (c^ (r&3)),
// read chunk lg ^ (row&3) -- same involution both sides.
__global__ __launch_bounds__(512, 2) void gemm_qkv_kernel(const short* __restrict__ Xb,
    const short* __restrict__ WtAll, short* __restrict__ Q, short* __restrict__ K,
    short* __restrict__ Vt){
  __shared__ __align__(16) short SH[49152];   // 96 KB: 3 slots x (A 8192 | B 8192)
  const int tid  = threadIdx.x;
  const int lane = tid & 63;
  const int wid  = tid >> 6;            // 0..7
  const int wm   = wid >> 2;            // 0..1  (m-half)
  const int wn   = wid & 3;             // 0..3  (n quarter)
  const int l15  = lane & 15, lg = lane >> 4;
  const int m0 = blockIdx.x * 256;
  const int n0 = blockIdx.y * 256;
  const int z  = blockIdx.z;
  const short* A  = Xb;
  const short* Bt = WtAll + z*(EMBED*EMBED);

  f32x4 acc[8][4] = {};                 // 128 VGPR accumulator

  const int sr = tid >> 2;              // stage row 0..127
  const int sc = tid & 3;               // stage chunk 0..3
  const int sp = sc ^ (sr & 3);         // pre-swizzled source chunk

  // stage whole K-tile t (A + B, both halves): 4 GLDS per thread
  auto STAGE_T = [&](int t){
    short* slot = SH + (t%3)*16384;
    #pragma unroll
    for (int mat=0; mat<2; ++mat){
      const short* src  = mat ? Bt : A;
      const int   base0 = mat ? n0 : m0;
      #pragma unroll
      for (int h=0; h<2; ++h)
        GLDS(src + (base0 + 128*h + sr)*1024 + t*32 + sp*8,
             slot + mat*8192 + h*4096 + tid*8);
    }
  };

  auto PHASE = [&](int t){
    const short* As = SH + (t%3)*16384;
    const short* Bs = As + 8192;
    bf16x8 a[8], b[4];
    #pragma unroll
    for (int i=0;i<8;++i){
      int row = wm*128 + 16*i + l15;
      a[i] = *(const bf16x8*)(As + row*32 + ((8*lg) ^ ((row&3)<<3)));
    }
    #pragma unroll
    for (int j=0;j<4;++j){
      int row = wn*64 + 16*j + l15;
      b[j] = *(const bf16x8*)(Bs + row*32 + ((8*lg) ^ ((row&3)<<3)));
    }
    BARRIER();
    __builtin_amdgcn_s_setprio(1);
    #pragma unroll
    for (int i=0;i<8;++i)
      #pragma unroll
      for (int j=0;j<4;++j)
        acc[i][j] = __builtin_amdgcn_mfma_f32_16x16x32_bf16(a[i], b[j], acc[i][j], 0,0,0);
    __builtin_amdgcn_s_setprio(0);
  };

  STAGE_T(0); STAGE_T(1);
  WAITV(4);                             // tile0 landed; tile1 in flight
  BARRIER();

  for (int t = 0; t < 32; ++t){
    if (t + 2 < 32) STAGE_T(t+2);       // -> slot of t-1 (free)
    PHASE(t);
    if (t + 2 < 32) { WAITV(4); }       // t+1's batch retired; t+2 in flight
    else            { WAITV(0); }       // tail drain
    BARRIER();
  }
  __syncthreads();

  const int bb = m0 >> 11, srow0 = m0 & 2047;
  if (z < 2){
    short* out = z ? K : Q;
    const float qscl = (z==0) ? (0.125f * 1.44269504f) : 1.0f;
    #pragma unroll
    for (int mi=0; mi<8; ++mi)
      #pragma unroll
      for (int nj=0; nj<4; ++nj)
        #pragma unroll
        for (int rr=0; rr<4; ++rr){
          int m = m0 + wm*128 + 16*mi + 4*lg + rr;
          int n = n0 + wn*64 + 16*nj + l15;
          int srow = m & 2047, hh = n >> 6, d = n & 63;
          out[(((bb<<4)+hh)*SEQL + srow)*HDIM + d] = f2bf(acc[mi][nj][rr] * qscl);
        }
  } else {
    // LDS transpose in two 128-n halves (64 KB each, fits 96 KB)
    short* T = SH;
    #pragma unroll
    for (int h=0; h<2; ++h){
      if ((wn >> 1) == h){
        #pragma unroll
        for (int mi=0; mi<8; ++mi)
          #pragma unroll
          for (int nj=0; nj<4; ++nj){
            int n_loc = (wn & 1)*64 + 16*nj + l15;       // 0..127
            int mb    = wm*128 + 16*mi + 4*lg;           // mult of 4
            short4 pk;
            pk.x = f2bf(acc[mi][nj][0]); pk.y = f2bf(acc[mi][nj][1]);
            pk.z = f2bf(acc[mi][nj][2]); pk.w = f2bf(acc[mi][nj][3]);
            *(short4*)(T + n_loc*256 + (mb ^ ((n_loc & 7) << 3))) = pk;
          }
      }
      __syncthreads();
      #pragma unroll
      for (int it=0; it<8; ++it){
        int ci    = it*512 + tid;
        int n_loc = ci >> 5;
        int mch   = (ci & 31) * 8;
        int4 v = *(const int4*)(T + n_loc*256 + (mch ^ ((n_loc & 7) << 3)));
        int n_glob = n0 + h*128 + n_loc;
        int hh = n_glob >> 6, d = n_glob & 63;
        *(int4*)(Vt + (((bb<<4)+hh)*HDIM + d)*SEQL + srow0 + mch) = v;
      }
      __syncthreads();
    }
  }
}

// ---- 64x128 bf16 GEMM mainloop, paired K-steps (R16, for out-GEMM) ---------
__device__ __forceinline__ void gemm_tile_64(const short* __restrict__ A,
    const short* __restrict__ Bt, short* As, short* Bs, int m0, int n0, f32x4 acc[2][4]){
  const int tid  = threadIdx.x;
  const int lane = tid & 63;
  const int wid  = tid >> 6;
  const int wrow = (wid >> 1) * 32, wcol = (wid & 1) * 64;
  const int arow = tid >> 2, acol8 = (tid & 3) * 8;
  const int l15 = lane & 15, lg = lane >> 4;

  auto STAGE = [&](int b, int k0){
    short* as = As + b*2048;
    short* bs = Bs + b*4096;
    GLDS(A  + (m0      + arow) * 1024 + k0 + acol8, as + tid*8);
    GLDS(Bt + (n0      + arow) * 1024 + k0 + acol8, bs + tid*8);
    GLDS(Bt + (n0 + 64 + arow) * 1024 + k0 + acol8, bs + 2048 + tid*8);
  };

  auto KSTEP = [&](int b){
    const short* as = As + b*2048;
    const short* bs = Bs + b*4096;
    bf16x8 a[2], bb[4];
    #pragma unroll
    for (int i=0;i<2;++i) a[i]  = *(const bf16x8*)(as + (wrow+16*i+l15)*32 + 8*lg);
    #pragma unroll
    for (int j=0;j<4;++j) bb[j] = *(const bf16x8*)(bs + (wcol+16*j+l15)*32 + 8*lg);
    #pragma unroll
    for (int i=0;i<2;++i)
      #pragma unroll
      for (int j=0;j<4;++j)
        acc[i][j] = __builtin_amdgcn_mfma_f32_16x16x32_bf16(a[i], bb[j], acc[i][j], 0,0,0);
  };

  STAGE(0, 0); STAGE(1, 32);
  __syncthreads();
  for (int p = 0; p < 16; ++p){
    const int k0 = p*64;
    if (p + 1 < 16){ STAGE((2*p+2)&3, k0+64); STAGE((2*p+3)&3, k0+96); }
    KSTEP((2*p)&3);
    KSTEP((2*p+1)&3);
    __syncthreads();
  }
}

// Output projection: out = Ctx @ W_o + b_o (fp32), BM=64
__global__ __launch_bounds__(256) void gemm_out_kernel(const short* __restrict__ Ctx,
    const short* __restrict__ WtO, const float* __restrict__ bias, float* __restrict__ out){
  __shared__ __align__(16) short As[4*2048], Bs[4*4096];
  const int m0 = blockIdx.x*64, n0 = blockIdx.y*128;
  f32x4 acc[2][4] = {};
  gemm_tile_64(Ctx, WtO, As, Bs, m0, n0, acc);
  const int lane = threadIdx.x & 63;
  const int wid  = threadIdx.x >> 6;
  const int wrow = (wid >> 1) * 32, wcol = (wid & 1) * 64;
  const int l15 = lane & 15, lg = lane >> 4;
  #pragma unroll
  for (int i=0;i<2;++i)
    #pragma unroll
    for (int j=0;j<4;++j)
      #pragma unroll
      for (int r=0;r<4;++r){
        int m = m0 + wrow + 16*i + 4*lg + r;
        int n = n0 + wcol + 16*j + l15;
        out[m*EMBED + n] = acc[i][j][r] + bias[n];
      }
}

// --- causal flash attention v12 (R15/R16, known-best): KV pair-processing ---
__global__ __launch_bounds__(512, 4) void attn_kernel(const short* __restrict__ Q,
    const short* __restrict__ K, const short* __restrict__ Vt, short* __restrict__ Ctx){
  __shared__ __align__(16) char lds[81920];   // KV bufs x4 (64 KB) | P (16 KB)
  const int tid  = threadIdx.x;
  const int lane = tid & 63;
  const int wid  = tid >> 6;             // 0..7
  const int bid   = blockIdx.x;          // 0..511
  const int xcd   = bid & 7;
  const int i7    = bid >> 3;            // 0..63 (per-XCD order)
  const int bh    = xcd + 8*(i7 & 3);    // 4 heads per XCD
  const int cidx  = i7 >> 2;             // 0..15
  const int chunk = (cidx < 8) ? cidx : 23 - cidx;  // CU-pair sums constant
  const int q0blk = chunk * 128;
  const int ntp   = chunk + 1;           // kv tile PAIRS for this block
  const int q0w   = q0blk + 16*wid;      // this wave's first q row
  const int qlast = q0w + 15;

  const short* Qh  = Q  + bh*(SEQL*HDIM);
  const char*  KhB = (const char*)(K  + bh*(SEQL*HDIM));
  const char*  VhB = (const char*)(Vt + bh*(HDIM*SEQL));
  const int l15 = lane & 15, lg = lane >> 4;
  const int lg20 = 20 * lg;
  const int swE = (l15 & 7) << 3;        // P swizzle (elements)
  const int swB = (l15 & 7) << 4;        // K/V read swizzle (bytes)
  const int laneRow = lane >> 3;                       // 0..7
  const int colSwz  = 16 * ((lane & 7) ^ laneRow);     // inverse swizzle
  const int r0 = 8 * wid;                              // this wave's stage rows

  const short* qp = Qh + (q0w + l15)*HDIM + 8*lg;
  bf16x8 bq0 = *(const bf16x8*)qp;
  bf16x8 bq1 = *(const bf16x8*)(qp + 32);

  f32x4 acc[4];                          // [j]: rows q=4lg+r, cols d=16j+l15
  #pragma unroll
  for (int j=0; j<4; ++j) acc[j] = (f32x4){0.f,0.f,0.f,0.f};
  float mrun = -3e30f, lrun = 0.f;       // per lane: state of q-row l15

  short* pw = (short*)(lds + 65536 + wid*2048);  // per-wave 16x64 bf16 P

  auto STAGE = [&](int b, int t){
    char* kb = lds + b*16384;
    char* vb = kb + 8192;
    const int kv0 = t*64;
    GLDS(KhB + (kv0 + r0 + laneRow)*128 + colSwz, kb + r0*128);
    GLDS(VhB + (r0 + laneRow)*4096 + kv0*2 + colSwz, vb + r0*128);
  };

  // QK^T for one 64-kv half from K-buffer kb -> sc[4]
  auto QKHALF = [&](const char* kb, f32x4 sc[4]){
    #pragma unroll
    for (int c=0; c<4; ++c){
      const char* kr = kb + (16*c + l15)*128;
      bf16x8 k0 = *(const bf16x8*)(kr + ((16*lg) ^ swB));
      bf16x8 k1 = *(const bf16x8*)(kr + ((64 + 16*lg) ^ swB));
      f32x4 zz = (f32x4){0.f,0.f,0.f,0.f};
      zz = __builtin_amdgcn_mfma_f32_16x16x32_bf16(k0, bq0, zz, 0,0,0);
      zz = __builtin_amdgcn_mfma_f32_16x16x32_bf16(k1, bq1, zz, 0,0,0);
      sc[c] = zz;
    }
  };

  STAGE(0, 0); STAGE(1, 1);
  __syncthreads();

  for (int tp = 0; tp < ntp; ++tp){
    const int t0   = 2*tp;
    const int kv00 = t0*64;
    const int kv01 = kv00 + 64;
    if (tp + 1 < ntp){ STAGE((t0+2)&3, t0+2); STAGE((t0+3)&3, t0+3); }
    if (kv00 <= qlast){
      const char* kb0 = lds + (t0&3)*16384;
      const char* kb1 = lds + ((t0+1)&3)*16384;
      const bool  h1  = (kv01 <= qlast);      // wave-uniform
      f32x4 sc0[4], sc1[4];
      __builtin_amdgcn_s_setprio(1);
      QKHALF(kb0, sc0);
      if (h1) QKHALF(kb1, sc1);
      __builtin_amdgcn_s_setprio(0);
      // causal mask
      if (kv00 + 63 > q0w){
        #pragma unroll
        for (int c=0; c<4; ++c)
          #pragma unroll
          for (int r=0; r<4; ++r)
            if (kv00 + 16*c + 4*lg + r > q0w + l15) sc0[c][r] = -3e30f;
      }
      if (h1 && kv01 + 63 > q0w){
        #pragma unroll
        for (int c=0; c<4; ++c)
          #pragma unroll
          for (int r=0; r<4; ++r)
            if (kv01 + 16*c + 4*lg + r > q0w + l15) sc1[c][r] = -3e30f;
      }
      // ONE online-softmax update per 128 kv; tree max; T13 defer-max
      float cm[4];
      #pragma unroll
      for (int c=0; c<4; ++c)
        cm[c] = fmaxf(fmaxf(sc0[c][0], sc0[c][1]), fmaxf(sc0[c][2], sc0[c][3]));
      float pm = fmaxf(fmaxf(cm[0], cm[1]), fmaxf(cm[2], cm[3]));
      if (h1){
        float dm[4];
        #pragma unroll
        for (int c=0; c<4; ++c)
          dm[c] = fmaxf(fmaxf(sc1[c][0], sc1[c][1]), fmaxf(sc1[c][2], sc1[c][3]));
        pm = fmaxf(pm, fmaxf(fmaxf(dm[0], dm[1]), fmaxf(dm[2], dm[3])));
      }
      pm = fmaxf(pm, __shfl_xor(pm, 16));
      pm = fmaxf(pm, __shfl_xor(pm, 32));
      const int resc = !__all(pm <= mrun);
      float mn = mrun, ss = 1.0f;
      if (resc){
        mn = fmaxf(mrun, pm);
        ss = __builtin_amdgcn_exp2f(mrun - mn);
        mrun = mn;
      }
      #pragma unroll
      for (int c=0; c<4; ++c)
        #pragma unroll
        for (int r=0; r<4; ++r)
          sc0[c][r] = __builtin_amdgcn_exp2f(sc0[c][r] - mn);
      float cs[4];
      #pragma unroll
      for (int c=0; c<4; ++c)
        cs[c] = (sc0[c][0] + sc0[c][1]) + (sc0[c][2] + sc0[c][3]);
      float ls = (cs[0] + cs[1]) + (cs[2] + cs[3]);
      if (h1){
        #pragma unroll
        for (int c=0; c<4; ++c)
          #pragma unroll
          for (int r=0; r<4; ++r)
            sc1[c][r] = __builtin_amdgcn_exp2f(sc1[c][r] - mn);
        float ds[4];
        #pragma unroll
        for (int c=0; c<4; ++c)
          ds[c] = (sc1[c][0] + sc1[c][1]) + (sc1[c][2] + sc1[c][3]);
        ls += (ds[0] + ds[1]) + (ds[2] + ds[3]);
      }
      ls += __shfl_xor(ls, 16);
      ls += __shfl_xor(ls, 32);
      if (resc){
        lrun = lrun*ss + ls;
        float srg[4];
        #pragma unroll
        for (int r=0; r<4; ++r) srg[r] = __shfl(ss, lg20 + r);
        #pragma unroll
        for (int j=0; j<4; ++j)
          #pragma unroll
          for (int r=0; r<4; ++r) acc[j][r] *= srg[r];
      } else {
        lrun += ls;
      }
      // half0: P -> LDS, PV from V buffer 0
      #pragma unroll
      for (int c=0; c<4; ++c){
        short4 pk;
        pk.x = f2bf(sc0[c][0]); pk.y = f2bf(sc0[c][1]);
        pk.z = f2bf(sc0[c][2]); pk.w = f2bf(sc0[c][3]);
        *(short4*)(pw + l15*64 + ((16*c + 4*lg) ^ swE)) = pk;
      }
      {
        bf16x8 pa0 = *(const bf16x8*)(pw + l15*64 + ((8*lg)      ^ swE));
        bf16x8 pa1 = *(const bf16x8*)(pw + l15*64 + ((32 + 8*lg) ^ swE));
        const char* vb = kb0 + 8192;
        __builtin_amdgcn_s_setprio(1);
        #pragma unroll
        for (int j=0; j<4; ++j){
          const char* vrp = vb + (16*j + l15)*128;
          bf16x8 v0 = *(const bf16x8*)(vrp + ((16*lg) ^ swB));
          bf16x8 v1 = *(const bf16x8*)(vrp + ((64 + 16*lg) ^ swB));
          acc[j] = __builtin_amdgcn_mfma_f32_16x16x32_bf16(pa0, v0, acc[j], 0,0,0);
          acc[j] = __builtin_amdgcn_mfma_f32_16x16x32_bf16(pa1, v1, acc[j], 0,0,0);
        }
        __builtin_amdgcn_s_setprio(0);
      }
      // half1: reuse P buffer (same-wave DS ops in order -> WAR-safe)
      if (h1){
        #pragma unroll
        for (int c=0; c<4; ++c){
          short4 pk;
          pk.x = f2bf(sc1[c][0]); pk.y = f2bf(sc1[c][1]);
          pk.z = f2bf(sc1[c][2]); pk.w = f2bf(sc1[c][3]);
          *(short4*)(pw + l15*64 + ((16*c + 4*lg) ^ swE)) = pk;
        }
        bf16x8 pa0 = *(const bf16x8*)(pw + l15*64 + ((8*lg)      ^ swE));
        bf16x8 pa1 = *(const bf16x8*)(pw + l15*64 + ((32 + 8*lg) ^ swE));
        const char* vb = kb1 + 8192;
        __builtin_amdgcn_s_setprio(1);
        #pragma unroll
        for (int j=0; j<4; ++j){
          const char* vrp = vb + (16*j + l15)*128;
          bf16x8 v0 = *(const bf16x8*)(vrp + ((16*lg) ^ swB));
          bf16x8 v1 = *(const bf16x8*)(vrp + ((64 + 16*lg) ^ swB));
          acc[j] = __builtin_amdgcn_mfma_f32_16x16x32_bf16(pa0, v0, acc[j], 0,0,0);
          acc[j] = __builtin_amdgcn_mfma_f32_16x16x32_bf16(pa1, v1, acc[j], 0,0,0);
        }
        __builtin_amdgcn_s_setprio(0);
      }
    }
    __syncthreads();
  }

  // epilogue: redistribute lrun to acc rows, scale, write ctx
  const int bb = bh >> 4, hh = bh & 15;
  float lr[4];
  #pragma unroll
  for (int r=0; r<4; ++r) lr[r] = __builtin_amdgcn_rcpf(__shfl(lrun, lg20 + r));
  #pragma unroll
  for (int j=0; j<4; ++j)
    #pragma unroll
    for (int r=0; r<4; ++r){
      int qg = q0w + 4*lg + r;
      Ctx[(bb*SEQL + qg)*EMBED + hh*HDIM + 16*j + l15] = f2bf(acc[j][r] * lr[r]);
    }
}

extern "C" void kernel_launch(void* const* d_in, const int* in_sizes, int n_in,
                              void* d_out, int out_size, void* d_ws, size_t ws_size,
                              hipStream_t stream){
  const float* x  = (const float*)d_in[0];
  const float* Wq = (const float*)d_in[1];
  const float* Wk = (const float*)d_in[2];
  const float* Wv = (const float*)d_in[3];
  const float* Wo = (const float*)d_in[4];
  const float* bo = (const float*)d_in[5];
  float* out = (float*)d_out;

  char* ws = (char*)d_ws;
  const size_t MB = 1u << 20;
  short* Xb  = (short*)(ws +  0*MB);  // [4096][1024] bf16 (8 MB)
  short* Wt  = (short*)(ws +  8*MB);  // 4x [1024][1024] bf16 transposed (8 MB)
  short* Q   = (short*)(ws + 16*MB);  // [b,h,s,d] (8 MB)
  short* Kk  = (short*)(ws + 24*MB);  // [b,h,s,d] (8 MB)
  short* Vt  = (short*)(ws + 32*MB);  // [b,h,d,s] (8 MB)
  short* Ctx = (short*)(ws + 40*MB);  // [b,s,e]   (8 MB)

  prep_kernel<<<dim3(32,32,8), 256, 0, stream>>>(x, Wq, Wk, Wv, Wo, Xb, Wt);
  gemm_qkv_kernel<<<dim3(16,4,3), 512, 0, stream>>>(Xb, Wt, Q, Kk, Vt);
  attn_kernel<<<512, 512, 0, stream>>>(Q, Kk, Vt, Ctx);
  gemm_out_kernel<<<dim3(64,8), 256, 0, stream>>>(Ctx, Wt + 3*(EMBED*EMBED), bo, out);
}

// Round 19
// 101.500 us; speedup vs baseline: 1.0389x; 1.0389x over previous
//
#include <hip/hip_runtime.h>

#define EMBED 1024
#define SEQL  2048
#define NHEAD 16
#define HDIM  64
#define NBATCH 2
#define MROWS 4096   // NBATCH*SEQL

typedef __attribute__((ext_vector_type(4))) float  f32x4;
typedef __attribute__((ext_vector_type(8))) __bf16 bf16x8;

// native HW bf16 convert (compiler fuses pairs into v_cvt_pk_bf16_f32)
__device__ __forceinline__ short f2bf(float f){
  __bf16 h = (__bf16)f;
  union { __bf16 h; short s; } u; u.h = h;
  return u.s;
}

#define GLDS(gp, lp) __builtin_amdgcn_global_load_lds( \
    (const __attribute__((address_space(1))) void*)(gp), \
    (__attribute__((address_space(3))) void*)(lp), 16, 0, 0)

// ------- prep: z=0..3 transpose W[z] fp32->bf16^T (64x64 float4 tiles);
//               z=4..7 convert x fp32->bf16 ------------------------------
__global__ __launch_bounds__(256) void prep_kernel(const float* __restrict__ x,
    const float* __restrict__ W0, const float* __restrict__ W1,
    const float* __restrict__ W2, const float* __restrict__ W3,
    short* __restrict__ Xb, short* __restrict__ WtAll){
  const int z = blockIdx.z;
  if (z < 4){
    __shared__ float T[64][65];          // 16.6 KB, +1 pad
    const int idx = blockIdx.y*32 + blockIdx.x;
    if (idx >= 256) return;              // 16x16 tiles of 64x64
    const float* W = (z==0)?W0:(z==1)?W1:(z==2)?W2:W3;
    short* Wt = WtAll + z*(EMBED*EMBED);
    const int bx = (idx & 15)*64;        // n-base
    const int by = (idx >> 4)*64;        // k-base
    const int c4 = (threadIdx.x & 15)*4;
    const int tr = threadIdx.x >> 4;     // 0..15
    #pragma unroll
    for (int i=0;i<4;++i){
      int r = 16*i + tr;
      float4 v = *(const float4*)(W + (by + r)*EMBED + bx + c4);
      T[c4+0][r] = v.x; T[c4+1][r] = v.y; T[c4+2][r] = v.z; T[c4+3][r] = v.w;
    }
    __syncthreads();
    #pragma unroll
    for (int i=0;i<4;++i){
      int n = 16*i + tr;
      short4 o;
      o.x = f2bf(T[n][c4+0]); o.y = f2bf(T[n][c4+1]);
      o.z = f2bf(T[n][c4+2]); o.w = f2bf(T[n][c4+3]);
      *(short4*)(Wt + (bx + n)*EMBED + by + c4) = o;
    }
  } else {
    const int blk = (z-4)*1024 + blockIdx.y*32 + blockIdx.x;
    const int i = (blk*256 + threadIdx.x)*4;
    float4 v = *(const float4*)(x + i);
    short4 o; o.x=f2bf(v.x); o.y=f2bf(v.y); o.z=f2bf(v.z); o.w=f2bf(v.w);
    *(short4*)(Xb + i) = o;
  }
}

// ---- 128x128 bf16 GEMM mainloop, PAIRED K-steps (eff. BK=64, R16-best) -----
// 4 rotating 8KB+8KB buffers; stage pair p+1 BEFORE computing pair p; ONE
// __syncthreads per 64-K. Compute/epoch (~600cy) > load latency -> barrier
// drain ~free; barrier count halved. WAR protected by previous barrier.
__device__ __forceinline__ void gemm_tile_128(const short* __restrict__ A,
    const short* __restrict__ Bt, short* As, short* Bs, int m0, int n0, f32x4 acc[4][4]){
  const int tid  = threadIdx.x;
  const int lane = tid & 63;
  const int wid  = tid >> 6;
  const int wrow = (wid >> 1) * 64, wcol = (wid & 1) * 64;
  const int arow = tid >> 2, acol8 = (tid & 3) * 8;
  const int l15 = lane & 15, lg = lane >> 4;

  auto STAGE = [&](int b, int k0){
    short* as = As + b*4096;
    short* bs = Bs + b*4096;
    GLDS(A  + (m0      + arow) * 1024 + k0 + acol8, as + tid*8);
    GLDS(A  + (m0 + 64 + arow) * 1024 + k0 + acol8, as + 2048 + tid*8);
    GLDS(Bt + (n0      + arow) * 1024 + k0 + acol8, bs + tid*8);
    GLDS(Bt + (n0 + 64 + arow) * 1024 + k0 + acol8, bs + 2048 + tid*8);
  };

  auto KSTEP = [&](int b){
    const short* as = As + b*4096;
    const short* bs = Bs + b*4096;
    bf16x8 a[4], bb[4];
    #pragma unroll
    for (int i=0;i<4;++i) a[i]  = *(const bf16x8*)(as + (wrow+16*i+l15)*32 + 8*lg);
    #pragma unroll
    for (int j=0;j<4;++j) bb[j] = *(const bf16x8*)(bs + (wcol+16*j+l15)*32 + 8*lg);
    #pragma unroll
    for (int i=0;i<4;++i)
      #pragma unroll
      for (int j=0;j<4;++j)
        acc[i][j] = __builtin_amdgcn_mfma_f32_16x16x32_bf16(a[i], bb[j], acc[i][j], 0,0,0);
  };

  STAGE(0, 0); STAGE(1, 32);
  __syncthreads();
  for (int p = 0; p < 16; ++p){
    const int k0 = p*64;
    if (p + 1 < 16){ STAGE((2*p+2)&3, k0+64); STAGE((2*p+3)&3, k0+96); }
    KSTEP((2*p)&3);
    KSTEP((2*p+1)&3);
    __syncthreads();
  }
}

// ---- 64x128 bf16 GEMM mainloop, same paired structure ----------------------
__device__ __forceinline__ void gemm_tile_64(const short* __restrict__ A,
    const short* __restrict__ Bt, short* As, short* Bs, int m0, int n0, f32x4 acc[2][4]){
  const int tid  = threadIdx.x;
  const int lane = tid & 63;
  const int wid  = tid >> 6;
  const int wrow = (wid >> 1) * 32, wcol = (wid & 1) * 64;
  const int arow = tid >> 2, acol8 = (tid & 3) * 8;
  const int l15 = lane & 15, lg = lane >> 4;

  auto STAGE = [&](int b, int k0){
    short* as = As + b*2048;
    short* bs = Bs + b*4096;
    GLDS(A  + (m0      + arow) * 1024 + k0 + acol8, as + tid*8);
    GLDS(Bt + (n0      + arow) * 1024 + k0 + acol8, bs + tid*8);
    GLDS(Bt + (n0 + 64 + arow) * 1024 + k0 + acol8, bs + 2048 + tid*8);
  };

  auto KSTEP = [&](int b){
    const short* as = As + b*2048;
    const short* bs = Bs + b*4096;
    bf16x8 a[2], bb[4];
    #pragma unroll
    for (int i=0;i<2;++i) a[i]  = *(const bf16x8*)(as + (wrow+16*i+l15)*32 + 8*lg);
    #pragma unroll
    for (int j=0;j<4;++j) bb[j] = *(const bf16x8*)(bs + (wcol+16*j+l15)*32 + 8*lg);
    #pragma unroll
    for (int i=0;i<2;++i)
      #pragma unroll
      for (int j=0;j<4;++j)
        acc[i][j] = __builtin_amdgcn_mfma_f32_16x16x32_bf16(a[i], bb[j], acc[i][j], 0,0,0);
  };

  STAGE(0, 0); STAGE(1, 32);
  __syncthreads();
  for (int p = 0; p < 16; ++p){
    const int k0 = p*64;
    if (p + 1 < 16){ STAGE((2*p+2)&3, k0+64); STAGE((2*p+3)&3, k0+96); }
    KSTEP((2*p)&3);
    KSTEP((2*p+1)&3);
    __syncthreads();
  }
}

// QKV projections: z=0 -> Q [b,h,s,d] (pre-scaled), z=1 -> K, z=2 -> V^T [b,h,d,s]
__global__ __launch_bounds__(256) void gemm_qkv_kernel(const short* __restrict__ Xb,
    const short* __restrict__ WtAll, short* __restrict__ Q, short* __restrict__ K,
    short* __restrict__ Vt){
  __shared__ __align__(16) short SH[32768];   // As: 4x4096, Bs: 4x4096 (64 KB)
  short* As = SH;
  short* Bs = SH + 16384;
  const int m0 = blockIdx.x*128, n0 = blockIdx.y*128, z = blockIdx.z;
  const short* Bt = WtAll + z*(EMBED*EMBED);
  f32x4 acc[4][4] = {};
  gemm_tile_128(Xb, Bt, As, Bs, m0, n0, acc);
  const int tid  = threadIdx.x;
  const int lane = tid & 63;
  const int wid  = tid >> 6;
  const int wrow = (wid >> 1) * 64, wcol = (wid & 1) * 64;
  const int l15 = lane & 15, lg = lane >> 4;
  const int bb = m0 >> 11, srow0 = m0 & 2047;

  if (z < 2){
    short* out = z ? K : Q;
    const float qscl = (z==0) ? (0.125f * 1.44269504f) : 1.0f;
    #pragma unroll
    for (int i=0;i<4;++i)
      #pragma unroll
      for (int j=0;j<4;++j)
        #pragma unroll
        for (int r=0;r<4;++r){
          int m = m0 + wrow + 16*i + 4*lg + r;
          int n = n0 + wcol + 16*j + l15;
          int srow = m & 2047, hh = n >> 6, d = n & 63;
          out[(((bb<<4)+hh)*SEQL + srow)*HDIM + d] = f2bf(acc[i][j][r] * qscl);
        }
  } else {
    // LDS transpose: T[n_loc][m_loc] bf16 (128x128 = 32 KB), m XOR-swizzled
    short* T = SH;                       // mainloop ended with a full barrier
    #pragma unroll
    for (int i=0;i<4;++i)
      #pragma unroll
      for (int j=0;j<4;++j){
        int n_loc = wcol + 16*j + l15;
        int mb    = wrow + 16*i + 4*lg;   // multiple of 4
        short4 pk;
        pk.x = f2bf(acc[i][j][0]); pk.y = f2bf(acc[i][j][1]);
        pk.z = f2bf(acc[i][j][2]); pk.w = f2bf(acc[i][j][3]);
        *(short4*)(T + n_loc*128 + (mb ^ ((n_loc & 7) << 3))) = pk;
      }
    __syncthreads();
    #pragma unroll
    for (int it=0; it<8; ++it){
      int n_loc = 16*it + (tid >> 4);
      int mch   = (tid & 15) * 8;
      int4 v = *(const int4*)(T + n_loc*128 + (mch ^ ((n_loc & 7) << 3)));
      int n_glob = n0 + n_loc;
      int hh = n_glob >> 6, d = n_glob & 63;
      *(int4*)(Vt + (((bb<<4)+hh)*HDIM + d)*SEQL + srow0 + mch) = v;
    }
  }
}

// Output projection: out = Ctx @ W_o + b_o (fp32), BM=64
__global__ __launch_bounds__(256) void gemm_out_kernel(const short* __restrict__ Ctx,
    const short* __restrict__ WtO, const float* __restrict__ bias, float* __restrict__ out){
  __shared__ __align__(16) short As[4*2048], Bs[4*4096];
  const int m0 = blockIdx.x*64, n0 = blockIdx.y*128;
  f32x4 acc[2][4] = {};
  gemm_tile_64(Ctx, WtO, As, Bs, m0, n0, acc);
  const int lane = threadIdx.x & 63;
  const int wid  = threadIdx.x >> 6;
  const int wrow = (wid >> 1) * 32, wcol = (wid & 1) * 64;
  const int l15 = lane & 15, lg = lane >> 4;
  #pragma unroll
  for (int i=0;i<2;++i)
    #pragma unroll
    for (int j=0;j<4;++j)
      #pragma unroll
      for (int r=0;r<4;++r){
        int m = m0 + wrow + 16*i + 4*lg + r;
        int n = n0 + wcol + 16*j + l15;
        out[m*EMBED + n] = acc[i][j][r] + bias[n];
      }
}

// --- causal flash attention v12 (R15/R16, known-best): KV pair-processing ---
__global__ __launch_bounds__(512, 4) void attn_kernel(const short* __restrict__ Q,
    const short* __restrict__ K, const short* __restrict__ Vt, short* __restrict__ Ctx){
  __shared__ __align__(16) char lds[81920];   // KV bufs x4 (64 KB) | P (16 KB)
  const int tid  = threadIdx.x;
  const int lane = tid & 63;
  const int wid  = tid >> 6;             // 0..7
  const int bid   = blockIdx.x;          // 0..511
  const int xcd   = bid & 7;
  const int i7    = bid >> 3;            // 0..63 (per-XCD order)
  const int bh    = xcd + 8*(i7 & 3);    // 4 heads per XCD
  const int cidx  = i7 >> 2;             // 0..15
  const int chunk = (cidx < 8) ? cidx : 23 - cidx;  // CU-pair sums constant
  const int q0blk = chunk * 128;
  const int ntp   = chunk + 1;           // kv tile PAIRS for this block
  const int q0w   = q0blk + 16*wid;      // this wave's first q row
  const int qlast = q0w + 15;

  const short* Qh  = Q  + bh*(SEQL*HDIM);
  const char*  KhB = (const char*)(K  + bh*(SEQL*HDIM));
  const char*  VhB = (const char*)(Vt + bh*(HDIM*SEQL));
  const int l15 = lane & 15, lg = lane >> 4;
  const int lg20 = 20 * lg;
  const int swE = (l15 & 7) << 3;        // P swizzle (elements)
  const int swB = (l15 & 7) << 4;        // K/V read swizzle (bytes)
  const int laneRow = lane >> 3;                       // 0..7
  const int colSwz  = 16 * ((lane & 7) ^ laneRow);     // inverse swizzle
  const int r0 = 8 * wid;                              // this wave's stage rows

  const short* qp = Qh + (q0w + l15)*HDIM + 8*lg;
  bf16x8 bq0 = *(const bf16x8*)qp;
  bf16x8 bq1 = *(const bf16x8*)(qp + 32);

  f32x4 acc[4];                          // [j]: rows q=4lg+r, cols d=16j+l15
  #pragma unroll
  for (int j=0; j<4; ++j) acc[j] = (f32x4){0.f,0.f,0.f,0.f};
  float mrun = -3e30f, lrun = 0.f;       // per lane: state of q-row l15

  short* pw = (short*)(lds + 65536 + wid*2048);  // per-wave 16x64 bf16 P

  auto STAGE = [&](int b, int t){
    char* kb = lds + b*16384;
    char* vb = kb + 8192;
    const int kv0 = t*64;
    GLDS(KhB + (kv0 + r0 + laneRow)*128 + colSwz, kb + r0*128);
    GLDS(VhB + (r0 + laneRow)*4096 + kv0*2 + colSwz, vb + r0*128);
  };

  // QK^T for one 64-kv half from K-buffer kb -> sc[4]
  auto QKHALF = [&](const char* kb, f32x4 sc[4]){
    #pragma unroll
    for (int c=0; c<4; ++c){
      const char* kr = kb + (16*c + l15)*128;
      bf16x8 k0 = *(const bf16x8*)(kr + ((16*lg) ^ swB));
      bf16x8 k1 = *(const bf16x8*)(kr + ((64 + 16*lg) ^ swB));
      f32x4 zz = (f32x4){0.f,0.f,0.f,0.f};
      zz = __builtin_amdgcn_mfma_f32_16x16x32_bf16(k0, bq0, zz, 0,0,0);
      zz = __builtin_amdgcn_mfma_f32_16x16x32_bf16(k1, bq1, zz, 0,0,0);
      sc[c] = zz;
    }
  };

  STAGE(0, 0); STAGE(1, 1);
  __syncthreads();

  for (int tp = 0; tp < ntp; ++tp){
    const int t0   = 2*tp;
    const int kv00 = t0*64;
    const int kv01 = kv00 + 64;
    if (tp + 1 < ntp){ STAGE((t0+2)&3, t0+2); STAGE((t0+3)&3, t0+3); }
    if (kv00 <= qlast){
      const char* kb0 = lds + (t0&3)*16384;
      const char* kb1 = lds + ((t0+1)&3)*16384;
      const bool  h1  = (kv01 <= qlast);      // wave-uniform
      f32x4 sc0[4], sc1[4];
      __builtin_amdgcn_s_setprio(1);
      QKHALF(kb0, sc0);
      if (h1) QKHALF(kb1, sc1);
      __builtin_amdgcn_s_setprio(0);
      // causal mask
      if (kv00 + 63 > q0w){
        #pragma unroll
        for (int c=0; c<4; ++c)
          #pragma unroll
          for (int r=0; r<4; ++r)
            if (kv00 + 16*c + 4*lg + r > q0w + l15) sc0[c][r] = -3e30f;
      }
      if (h1 && kv01 + 63 > q0w){
        #pragma unroll
        for (int c=0; c<4; ++c)
          #pragma unroll
          for (int r=0; r<4; ++r)
            if (kv01 + 16*c + 4*lg + r > q0w + l15) sc1[c][r] = -3e30f;
      }
      // ONE online-softmax update per 128 kv; tree max; T13 defer-max
      float cm[4];
      #pragma unroll
      for (int c=0; c<4; ++c)
        cm[c] = fmaxf(fmaxf(sc0[c][0], sc0[c][1]), fmaxf(sc0[c][2], sc0[c][3]));
      float pm = fmaxf(fmaxf(cm[0], cm[1]), fmaxf(cm[2], cm[3]));
      if (h1){
        float dm[4];
        #pragma unroll
        for (int c=0; c<4; ++c)
          dm[c] = fmaxf(fmaxf(sc1[c][0], sc1[c][1]), fmaxf(sc1[c][2], sc1[c][3]));
        pm = fmaxf(pm, fmaxf(fmaxf(dm[0], dm[1]), fmaxf(dm[2], dm[3])));
      }
      pm = fmaxf(pm, __shfl_xor(pm, 16));
      pm = fmaxf(pm, __shfl_xor(pm, 32));
      const int resc = !__all(pm <= mrun);
      float mn = mrun, ss = 1.0f;
      if (resc){
        mn = fmaxf(mrun, pm);
        ss = __builtin_amdgcn_exp2f(mrun - mn);
        mrun = mn;
      }
      #pragma unroll
      for (int c=0; c<4; ++c)
        #pragma unroll
        for (int r=0; r<4; ++r)
          sc0[c][r] = __builtin_amdgcn_exp2f(sc0[c][r] - mn);
      float cs[4];
      #pragma unroll
      for (int c=0; c<4; ++c)
        cs[c] = (sc0[c][0] + sc0[c][1]) + (sc0[c][2] + sc0[c][3]);
      float ls = (cs[0] + cs[1]) + (cs[2] + cs[3]);
      if (h1){
        #pragma unroll
        for (int c=0; c<4; ++c)
          #pragma unroll
          for (int r=0; r<4; ++r)
            sc1[c][r] = __builtin_amdgcn_exp2f(sc1[c][r] - mn);
        float ds[4];
        #pragma unroll
        for (int c=0; c<4; ++c)
          ds[c] = (sc1[c][0] + sc1[c][1]) + (sc1[c][2] + sc1[c][3]);
        ls += (ds[0] + ds[1]) + (ds[2] + ds[3]);
      }
      ls += __shfl_xor(ls, 16);
      ls += __shfl_xor(ls, 32);
      if (resc){
        lrun = lrun*ss + ls;
        float srg[4];
        #pragma unroll
        for (int r=0; r<4; ++r) srg[r] = __shfl(ss, lg20 + r);
        #pragma unroll
        for (int j=0; j<4; ++j)
          #pragma unroll
          for (int r=0; r<4; ++r) acc[j][r] *= srg[r];
      } else {
        lrun += ls;
      }
      // half0: P -> LDS, PV from V buffer 0
      #pragma unroll
      for (int c=0; c<4; ++c){
        short4 pk;
        pk.x = f2bf(sc0[c][0]); pk.y = f2bf(sc0[c][1]);
        pk.z = f2bf(sc0[c][2]); pk.w = f2bf(sc0[c][3]);
        *(short4*)(pw + l15*64 + ((16*c + 4*lg) ^ swE)) = pk;
      }
      {
        bf16x8 pa0 = *(const bf16x8*)(pw + l15*64 + ((8*lg)      ^ swE));
        bf16x8 pa1 = *(const bf16x8*)(pw + l15*64 + ((32 + 8*lg) ^ swE));
        const char* vb = kb0 + 8192;
        __builtin_amdgcn_s_setprio(1);
        #pragma unroll
        for (int j=0; j<4; ++j){
          const char* vrp = vb + (16*j + l15)*128;
          bf16x8 v0 = *(const bf16x8*)(vrp + ((16*lg) ^ swB));
          bf16x8 v1 = *(const bf16x8*)(vrp + ((64 + 16*lg) ^ swB));
          acc[j] = __builtin_amdgcn_mfma_f32_16x16x32_bf16(pa0, v0, acc[j], 0,0,0);
          acc[j] = __builtin_amdgcn_mfma_f32_16x16x32_bf16(pa1, v1, acc[j], 0,0,0);
        }
        __builtin_amdgcn_s_setprio(0);
      }
      // half1: reuse P buffer (same-wave DS ops in order -> WAR-safe)
      if (h1){
        #pragma unroll
        for (int c=0; c<4; ++c){
          short4 pk;
          pk.x = f2bf(sc1[c][0]); pk.y = f2bf(sc1[c][1]);
          pk.z = f2bf(sc1[c][2]); pk.w = f2bf(sc1[c][3]);
          *(short4*)(pw + l15*64 + ((16*c + 4*lg) ^ swE)) = pk;
        }
        bf16x8 pa0 = *(const bf16x8*)(pw + l15*64 + ((8*lg)      ^ swE));
        bf16x8 pa1 = *(const bf16x8*)(pw + l15*64 + ((32 + 8*lg) ^ swE));
        const char* vb = kb1 + 8192;
        __builtin_amdgcn_s_setprio(1);
        #pragma unroll
        for (int j=0; j<4; ++j){
          const char* vrp = vb + (16*j + l15)*128;
          bf16x8 v0 = *(const bf16x8*)(vrp + ((16*lg) ^ swB));
          bf16x8 v1 = *(const bf16x8*)(vrp + ((64 + 16*lg) ^ swB));
          acc[j] = __builtin_amdgcn_mfma_f32_16x16x32_bf16(pa0, v0, acc[j], 0,0,0);
          acc[j] = __builtin_amdgcn_mfma_f32_16x16x32_bf16(pa1, v1, acc[j], 0,0,0);
        }
        __builtin_amdgcn_s_setprio(0);
      }
    }
    __syncthreads();
  }

  // epilogue: redistribute lrun to acc rows, scale, write ctx
  const int bb = bh >> 4, hh = bh & 15;
  float lr[4];
  #pragma unroll
  for (int r=0; r<4; ++r) lr[r] = __builtin_amdgcn_rcpf(__shfl(lrun, lg20 + r));
  #pragma unroll
  for (int j=0; j<4; ++j)
    #pragma unroll
    for (int r=0; r<4; ++r){
      int qg = q0w + 4*lg + r;
      Ctx[(bb*SEQL + qg)*EMBED + hh*HDIM + 16*j + l15] = f2bf(acc[j][r] * lr[r]);
    }
}

extern "C" void kernel_launch(void* const* d_in, const int* in_sizes, int n_in,
                              void* d_out, int out_size, void* d_ws, size_t ws_size,
                              hipStream_t stream){
  const float* x  = (const float*)d_in[0];
  const float* Wq = (const float*)d_in[1];
  const float* Wk = (const float*)d_in[2];
  const float* Wv = (const float*)d_in[3];
  const float* Wo = (const float*)d_in[4];
  const float* bo = (const float*)d_in[5];
  float* out = (float*)d_out;

  char* ws = (char*)d_ws;
  const size_t MB = 1u << 20;
  short* Xb  = (short*)(ws +  0*MB);  // [4096][1024] bf16 (8 MB)
  short* Wt  = (short*)(ws +  8*MB);  // 4x [1024][1024] bf16 transposed (8 MB)
  short* Q   = (short*)(ws + 16*MB);  // [b,h,s,d] (8 MB)
  short* Kk  = (short*)(ws + 24*MB);  // [b,h,s,d] (8 MB)
  short* Vt  = (short*)(ws + 32*MB);  // [b,h,d,s] (8 MB)
  short* Ctx = (short*)(ws + 40*MB);  // [b,s,e]   (8 MB)

  prep_kernel<<<dim3(32,32,8), 256, 0, stream>>>(x, Wq, Wk, Wv, Wo, Xb, Wt);
  gemm_qkv_kernel<<<dim3(32,8,3), 256, 0, stream>>>(Xb, Wt, Q, Kk, Vt);
  attn_kernel<<<512, 512, 0, stream>>>(Q, Kk, Vt, Ctx);
  gemm_out_kernel<<<dim3(64,8), 256, 0, stream>>>(Ctx, Wt + 3*(EMBED*EMBED), bo, out);
}